// Round 3
// baseline (1840.536 us; speedup 1.0000x reference)
//
#include <hip/hip_runtime.h>

// h_t = f_t * h_{t-1} + (1 - f_t) * z_t over [T=1024, B, H], scan along T.
//
// Single-pass chunked scan with decoupled lookback:
//   - T split into K_CHUNKS chunks of L_STEPS.
//   - Block = 256 threads = 256 channels, one chunk. Grid = groups * K.
//   - Each block register-loads its chunk (64 loads issued back-to-back ->
//     deep MLP), computes (A = prod f, B = local scan), waits on predecessor
//     chunk's per-channel carry, publishes its own, then writes outputs.
//   - Dynamic block ordinal (atomicAdd) guarantees chunk k-1 acquired before
//     chunk k -> deadlock-free regardless of HW dispatch order.
//   - Agent-scope atomics for carries/flags (per-XCD L2s not coherent).

constexpr int T_STEPS  = 1024;
constexpr int K_CHUNKS = 32;
constexpr int L_STEPS  = T_STEPS / K_CHUNKS;   // 32
constexpr int BLOCK    = 256;

// d_ws layout: [0] counter (4B) | [1024] flags (K*groups u32) | [32768] carries
constexpr size_t WS_FLAGS_OFF = 1024;
constexpr size_t WS_CARRY_OFF = 32768;

__global__ __launch_bounds__(BLOCK) void fm_lookback(
    const float* __restrict__ f, const float* __restrict__ z,
    float* __restrict__ h,
    unsigned int* __restrict__ counter, unsigned int* __restrict__ flags,
    float* __restrict__ carry, int BH, int groups)
{
    __shared__ unsigned int s_ord;
    if (threadIdx.x == 0) s_ord = atomicAdd(counter, 1u);
    __syncthreads();
    const unsigned int ord = s_ord;
    const int k = (int)(ord / (unsigned)groups);
    const int g = (int)(ord % (unsigned)groups);
    const int c = g * BLOCK + (int)threadIdx.x;

    const size_t stride = (size_t)BH;
    const size_t base   = (size_t)k * L_STEPS * stride + (size_t)c;

    // ---- issue all chunk loads back-to-back (64 outstanding) ----
    float fv[L_STEPS], zv[L_STEPS];
#pragma unroll
    for (int i = 0; i < L_STEPS; ++i) {
        fv[i] = f[base + (size_t)i * stride];
        zv[i] = z[base + (size_t)i * stride];
    }

    // ---- chunk summary: h_local = A * h_in + B ----
    float A = 1.0f, B = 0.0f;
#pragma unroll
    for (int i = 0; i < L_STEPS; ++i) {
        B = fv[i] * (B - zv[i]) + zv[i];   // B = f*B + (1-f)*z
        A *= fv[i];
    }

    // ---- lookback: wait for predecessor chunk's carry ----
    float Hprev = 0.0f;
    if (k > 0) {
        if (threadIdx.x == 0) {
            const unsigned int* flg = &flags[(size_t)(k - 1) * groups + g];
            while (__hip_atomic_load(flg, __ATOMIC_ACQUIRE,
                                     __HIP_MEMORY_SCOPE_AGENT) == 0u) {
                __builtin_amdgcn_s_sleep(2);
            }
        }
        __syncthreads();
        Hprev = __hip_atomic_load(&carry[(size_t)(k - 1) * BH + c],
                                  __ATOMIC_RELAXED, __HIP_MEMORY_SCOPE_AGENT);
    }

    // ---- publish our carry ASAP ----
    if (k < K_CHUNKS - 1) {
        const float Hk = A * Hprev + B;
        __hip_atomic_store(&carry[(size_t)k * BH + c], Hk,
                           __ATOMIC_RELAXED, __HIP_MEMORY_SCOPE_AGENT);
        __threadfence();          // drain this thread's store to agent scope
        __syncthreads();          // all 256 carry stores drained
        if (threadIdx.x == 0)
            __hip_atomic_store(&flags[(size_t)k * groups + g], 1u,
                               __ATOMIC_RELEASE, __HIP_MEMORY_SCOPE_AGENT);
    }

    // ---- final outputs ----
    float hv = Hprev;
#pragma unroll
    for (int i = 0; i < L_STEPS; ++i) {
        hv = fv[i] * (hv - zv[i]) + zv[i];
        h[base + (size_t)i * stride] = hv;
    }
}

// Fallback (no workspace needed): R2-style sequential-per-channel scan.
__global__ __launch_bounds__(64) void fm_scan_simple(
    const float* __restrict__ f, const float* __restrict__ z,
    float* __restrict__ h, int BH)
{
    const int ch = blockIdx.x * blockDim.x + threadIdx.x;
    if (ch >= BH) return;
    const size_t stride = (size_t)BH;
    float hv = 0.0f;
    for (int t = 0; t < T_STEPS; ++t) {
        const float fv = f[(size_t)t * stride + ch];
        const float zv = z[(size_t)t * stride + ch];
        hv = fv * (hv - zv) + zv;
        h[(size_t)t * stride + ch] = hv;
    }
}

extern "C" void kernel_launch(void* const* d_in, const int* in_sizes, int n_in,
                              void* d_out, int out_size, void* d_ws, size_t ws_size,
                              hipStream_t stream) {
    const float* f = (const float*)d_in[0];
    const float* z = (const float*)d_in[1];
    float*       h = (float*)d_out;

    const int BH     = in_sizes[0] / T_STEPS;   // 32*1024 = 32768
    const int groups = BH / BLOCK;              // 128

    const size_t ws_needed = WS_CARRY_OFF + (size_t)K_CHUNKS * BH * sizeof(float);

    if ((BH % BLOCK) == 0 && ws_size >= ws_needed) {
        char* ws = (char*)d_ws;
        unsigned int* counter = (unsigned int*)ws;
        unsigned int* flags   = (unsigned int*)(ws + WS_FLAGS_OFF);
        float*        carry   = (float*)(ws + WS_CARRY_OFF);

        // reset counter + flags each call (harness does not re-poison)
        hipMemsetAsync(d_ws, 0,
                       WS_FLAGS_OFF + (size_t)K_CHUNKS * groups * sizeof(unsigned int),
                       stream);

        const int grid = K_CHUNKS * groups;     // 4096 blocks
        fm_lookback<<<grid, BLOCK, 0, stream>>>(f, z, h, counter, flags, carry,
                                                BH, groups);
    } else {
        const int block = 64;
        const int grid  = (BH + block - 1) / block;
        fm_scan_simple<<<grid, block, 0, stream>>>(f, z, h, BH);
    }
}

// Round 5
// 89.004 us; speedup vs baseline: 20.6792x; 20.6792x over previous
//
#include <hip/hip_runtime.h>
#include <cstdint>

// h_t = f_t * h_{t-1} + (1 - f_t) * z_t over [T=1024, B, H], scan along T.
//
// One wave (64 threads) per block, 64 channels per block, coalesced 256 B per
// global_load_lds instruction. Pipeline state lives in an LDS ring buffer
// (NSLOT slots x BATCH timesteps), filled by async global_load_lds issued
// LOOKAHEAD batches ahead, consumed after a hand-counted s_waitcnt vmcnt(N).
// No __syncthreads anywhere (1 wave/block) -> no compiler vmcnt(0) drains.

constexpr int T_STEPS   = 1024;
constexpr int BATCH     = 16;                 // timesteps per ring slot
constexpr int NSLOT     = 4;                  // ring depth
constexpr int NPHASE    = T_STEPS / BATCH;    // 64
constexpr int LOOKAHEAD = NSLOT - 1;          // 3 batches in flight

typedef const __attribute__((address_space(1))) unsigned int* gp1_t;
typedef __attribute__((address_space(3))) unsigned int* lp3_t;

__global__ __launch_bounds__(64, 1) void fm_scan_lds(const float* __restrict__ f,
                                                     const float* __restrict__ z,
                                                     float* __restrict__ h,
                                                     int BH) {
    __shared__ float lf[NSLOT][BATCH][64];
    __shared__ float lz[NSLOT][BATCH][64];

    const int lane = (int)threadIdx.x;
    const int ch   = (int)blockIdx.x * 64 + lane;
    const size_t stride = (size_t)BH;

    const float* fp = f + ch;   // per-lane global base
    const float* zp = z + ch;
    float*       hp = h + ch;

    // Issue one batch: 32 async global->LDS loads (each 64 lanes x 4 B).
    auto issue = [&](int b) {
        const int s = b & (NSLOT - 1);
#pragma unroll
        for (int i = 0; i < BATCH; ++i) {
            const size_t off = (size_t)(b * BATCH + i) * stride;
            __builtin_amdgcn_global_load_lds((gp1_t)(const void*)(fp + off),
                                             (lp3_t)(void*)&lf[s][i][0], 4, 0, 0);
            __builtin_amdgcn_global_load_lds((gp1_t)(const void*)(zp + off),
                                             (lp3_t)(void*)&lz[s][i][0], 4, 0, 0);
        }
    };

    // Prologue: LOOKAHEAD batches in flight (issue stalls at the 63-op HW cap,
    // which is exactly the throughput governor we want).
    issue(0);
    issue(1);
    issue(2);

    float hv = 0.0f;

#pragma unroll 1
    for (int p = 0; p < NPHASE; ++p) {
        if (p + LOOKAHEAD < NPHASE) issue(p + LOOKAHEAD);

        // Guarantee batch p's 32 loads have landed in LDS.
        // Steady state: newest 48 ops = next batch's 32 loads + 16 stores.
        if (p < NPHASE - 2) {
            asm volatile("s_waitcnt vmcnt(48)" ::: "memory");
        } else if (p == NPHASE - 2) {
            asm volatile("s_waitcnt vmcnt(32)" ::: "memory");
        } else {
            asm volatile("s_waitcnt vmcnt(0)" ::: "memory");
        }
        __builtin_amdgcn_sched_barrier(0);

        const int s = p & (NSLOT - 1);
#pragma unroll
        for (int i = 0; i < BATCH; ++i) {
            const float fv = lf[s][i][lane];
            const float zv = lz[s][i][lane];
            // h = f*h + (1-f)*z  ==  f*(h - z) + z
            hv = fv * (hv - zv) + zv;
            hp[(size_t)(p * BATCH + i) * stride] = hv;
        }
    }
}

// Fallback for unexpected shapes: plain sequential-per-channel scan.
__global__ __launch_bounds__(64) void fm_scan_simple(const float* __restrict__ f,
                                                     const float* __restrict__ z,
                                                     float* __restrict__ h,
                                                     int BH, int T) {
    const int ch = blockIdx.x * blockDim.x + threadIdx.x;
    if (ch >= BH) return;
    const size_t stride = (size_t)BH;
    float hv = 0.0f;
    for (int t = 0; t < T; ++t) {
        const float fv = f[(size_t)t * stride + ch];
        const float zv = z[(size_t)t * stride + ch];
        hv = fv * (hv - zv) + zv;
        h[(size_t)t * stride + ch] = hv;
    }
}

extern "C" void kernel_launch(void* const* d_in, const int* in_sizes, int n_in,
                              void* d_out, int out_size, void* d_ws, size_t ws_size,
                              hipStream_t stream) {
    const float* f = (const float*)d_in[0];
    const float* z = (const float*)d_in[1];
    float*       h = (float*)d_out;

    const int BH = in_sizes[0] / T_STEPS;   // 32*1024 = 32768 channels

    if ((BH % 64) == 0) {
        const int grid = BH / 64;           // 512 blocks = 2 waves/CU
        fm_scan_lds<<<grid, 64, 0, stream>>>(f, z, h, BH);
    } else {
        const int block = 64;
        const int grid  = (BH + block - 1) / block;
        fm_scan_simple<<<grid, block, 0, stream>>>(f, z, h, BH, T_STEPS);
    }
}

// Round 6
// 85.064 us; speedup vs baseline: 21.6371x; 1.0463x over previous
//
#include <hip/hip_runtime.h>
#include <cstdint>

// h_t = f_t * h_{t-1} + (1 - f_t) * z_t over [T=1024, B, H], scan along T.
//
// One wave per block, 64 channels per block (lane = channel). All global
// traffic is dwordx4 (1 KB per wave-op) to beat the vmcnt 63-op in-flight
// ceiling: lane l covers row t + l/16, bytes (l&15)*16 of the block's 256 B
// column strip. global_load_lds width=16 deposits that pattern as a linear
// [4 rows][64 ch] LDS tile (per-lane SOURCE addresses are allowed; LDS dest
// is base + lane*16). Outputs are staged in a [16][64] LDS tile and written
// back as float4 with the same lane pattern. Counted s_waitcnt vmcnt(N)
// (never 0 until the last phase), no __syncthreads anywhere.

constexpr int T_STEPS = 1024;
constexpr int BATCH   = 16;                 // timesteps per ring slot
constexpr int NPHASE  = T_STEPS / BATCH;    // 64
constexpr int NSLOT   = 6;                  // ring depth (> LA)
constexpr int LA      = 5;                  // lookahead batches

typedef const __attribute__((address_space(1))) unsigned int* gp1_t;
typedef __attribute__((address_space(3))) unsigned int* lp3_t;

__global__ __launch_bounds__(64, 1) void fm_scan_x4(const float* __restrict__ f,
                                                    const float* __restrict__ z,
                                                    float* __restrict__ h,
                                                    int BH) {
    __shared__ float lf[NSLOT][BATCH][64];
    __shared__ float lz[NSLOT][BATCH][64];
    __shared__ float lo[BATCH][64];

    const int lane = (int)threadIdx.x;
    const uint64_t stride4 = (uint64_t)BH * 4u;           // bytes per timestep row
    const char* fb = (const char*)f + (uint64_t)blockIdx.x * 256u;
    const char* zb = (const char*)z + (uint64_t)blockIdx.x * 256u;
    char*       hb = (char*)h       + (uint64_t)blockIdx.x * 256u;
    // lane l -> row (l>>4), bytes (l&15)*16 within the block's 256 B strip
    const uint64_t lane_off = (uint64_t)(lane >> 4) * stride4
                            + (uint64_t)(lane & 15) * 16u;
    const uint64_t lo_off   = (uint64_t)(lane >> 4) * 256u
                            + (uint64_t)(lane & 15) * 16u;

    // Issue one batch = 16 timesteps: 4+4 dwordx4 global->LDS ops (1 KB each).
    auto issue = [&](int b) {
        const int s = b % NSLOT;
#pragma unroll
        for (int q = 0; q < 4; ++q) {
            const uint64_t roff = (uint64_t)(b * BATCH + 4 * q) * stride4 + lane_off;
            __builtin_amdgcn_global_load_lds((gp1_t)(const void*)(fb + roff),
                                             (lp3_t)(void*)&lf[s][4 * q][0], 16, 0, 0);
            __builtin_amdgcn_global_load_lds((gp1_t)(const void*)(zb + roff),
                                             (lp3_t)(void*)&lz[s][4 * q][0], 16, 0, 0);
        }
    };

    // Prologue: LA batches in flight (40 ops).
    issue(0); issue(1); issue(2); issue(3); issue(4);

    float hv = 0.0f;

#pragma unroll 1
    for (int p = 0; p < NPHASE; ++p) {
        if (p + LA < NPHASE) issue(p + LA);

        // Wait until batch p's 8 loads landed (FIFO vmcnt; N = ops newer than
        // batch p's last load, stores counted only where they must exist).
        if (p < LA) {
            asm volatile("s_waitcnt vmcnt(40)" ::: "memory");
        } else if (p <= NPHASE - LA - 1) {           // steady: 8*5 loads + 4*5 stores
            asm volatile("s_waitcnt vmcnt(60)" ::: "memory");
        } else if (p == NPHASE - 5) {
            asm volatile("s_waitcnt vmcnt(32)" ::: "memory");
        } else if (p == NPHASE - 4) {
            asm volatile("s_waitcnt vmcnt(24)" ::: "memory");
        } else if (p == NPHASE - 3) {
            asm volatile("s_waitcnt vmcnt(16)" ::: "memory");
        } else if (p == NPHASE - 2) {
            asm volatile("s_waitcnt vmcnt(8)" ::: "memory");
        } else {
            asm volatile("s_waitcnt vmcnt(0)" ::: "memory");
        }
        __builtin_amdgcn_sched_barrier(0);

        // Sequential recurrence over this batch; stage outputs in LDS.
        const int s = p % NSLOT;
#pragma unroll
        for (int i = 0; i < BATCH; ++i) {
            const float fv = lf[s][i][lane];
            const float zv = lz[s][i][lane];
            hv = fv * (hv - zv) + zv;     // h = f*h + (1-f)*z
            lo[i][lane] = hv;
        }
        // Cross-lane LDS visibility before the transposed read-back (same wave,
        // no __syncthreads needed).
        asm volatile("s_waitcnt lgkmcnt(0)" ::: "memory");
        __builtin_amdgcn_sched_barrier(0);

        // Write the 16x64 tile as 4 dwordx4 ops with the same lane pattern.
#pragma unroll
        for (int q = 0; q < 4; ++q) {
            const float4 v = *(const float4*)((const char*)&lo[4 * q][0] + lo_off);
            *(float4*)(hb + (uint64_t)(p * BATCH + 4 * q) * stride4 + lane_off) = v;
        }
    }
}

// Fallback for unexpected shapes: plain sequential-per-channel scan.
__global__ __launch_bounds__(64) void fm_scan_simple(const float* __restrict__ f,
                                                     const float* __restrict__ z,
                                                     float* __restrict__ h,
                                                     int BH, int T) {
    const int ch = blockIdx.x * blockDim.x + threadIdx.x;
    if (ch >= BH) return;
    const size_t stride = (size_t)BH;
    float hv = 0.0f;
    for (int t = 0; t < T; ++t) {
        const float fv = f[(size_t)t * stride + ch];
        const float zv = z[(size_t)t * stride + ch];
        hv = fv * (hv - zv) + zv;
        h[(size_t)t * stride + ch] = hv;
    }
}

extern "C" void kernel_launch(void* const* d_in, const int* in_sizes, int n_in,
                              void* d_out, int out_size, void* d_ws, size_t ws_size,
                              hipStream_t stream) {
    const float* f = (const float*)d_in[0];
    const float* z = (const float*)d_in[1];
    float*       h = (float*)d_out;

    const int BH = in_sizes[0] / T_STEPS;   // 32*1024 = 32768 channels

    if ((BH % 64) == 0 && (BH * 16) % 256 == 0) {
        const int grid = BH / 64;           // 512 blocks, 1 wave each
        fm_scan_x4<<<grid, 64, 0, stream>>>(f, z, h, BH);
    } else {
        const int block = 64;
        const int grid  = (BH + block - 1) / block;
        fm_scan_simple<<<grid, block, 0, stream>>>(f, z, h, BH, T_STEPS);
    }
}